// Round 10
// baseline (1103.293 us; speedup 1.0000x reference)
//
#include <hip/hip_runtime.h>
#include <stdint.h>

// ---------------------------------------------------------------------------
// StageNet forward on MI355X — ROUND 21.
// R20: 993us = gemm 490 + scan ~430 + prep/final ~75. Relaxed-agent atomics
// validated as the cheap cross-block path (no L2 flush).
// Gemm model: per-CU staging-byte wall. 128^2 tiles stage 5.4GB total at
// ~55GB/s/CU -> ~385us floor (measured 490). Bigger tile is the only lever.
// This round: BM=BN=256 gather GEMM (350 blocks = 50 t-tiles x 7 g-panels),
// 512 thr / 8 waves (2Mx4N), same verified 2-barrier swizzled-GLL schedule:
//  * staged bytes 5.4 -> 2.9GB; MFMA:ds_read 1:1 -> 2.7:1.
//  * m-tile = one full t (m0 = tq*256) -> id gather = all 256 b rows;
//    ids register-cached per kt-pair (no idS; LDS 64KB).
//  * WkP padded to 1792 rows; panel-clustered bijective XCD map (350 jobs).
// Predicted: gemm 300-360us (MfmaUtil 45-55%), total ~800-870us.
// Fallback on regression: R20 gemm.
// ---------------------------------------------------------------------------

typedef unsigned short u16;
typedef short bf16x8 __attribute__((ext_vector_type(8)));
typedef float f32x4 __attribute__((ext_vector_type(4)));

#define GLL(gp, lp)                                                            \
  __builtin_amdgcn_global_load_lds(                                            \
      (const __attribute__((address_space(1))) unsigned int*)(gp),             \
      (__attribute__((address_space(3))) unsigned int*)(lp), 16, 0, 0)

__device__ __forceinline__ float bf2f(u16 u) {
  union { unsigned int i; float f; } v;
  v.i = ((unsigned int)u) << 16;
  return v.f;
}
__device__ __forceinline__ u16 f2bf(float f) {
  union { float f; unsigned int i; } v;
  v.f = f;
  unsigned int r = (v.i + 0x7fffu + ((v.i >> 16) & 1u)) >> 16;
  return (u16)r;
}
__device__ __forceinline__ float ldf(const void* p, size_t i, int isbf) {
  return isbf ? bf2f(((const u16*)p)[i]) : ((const float*)p)[i];
}
__device__ __forceinline__ float sigf(float x) { return 1.f / (1.f + __expf(-x)); }
__device__ __forceinline__ float tanhf_(float x) {
  float cx = fminf(fmaxf(x, -15.f), 15.f);
  float e = __expf(2.f * cx);
  return (e - 1.f) / (e + 1.f);
}
__device__ __forceinline__ float dot8_bf(const u16* w, const float* lp) {
  uint4 wv = *(const uint4*)w;
  union { unsigned int u; float f; } a0, a1;
  float s;
  a0.u = wv.x << 16; a1.u = wv.x & 0xffff0000u;
  s = lp[0] * a0.f + lp[1] * a1.f;
  a0.u = wv.y << 16; a1.u = wv.y & 0xffff0000u;
  s += lp[2] * a0.f + lp[3] * a1.f;
  a0.u = wv.z << 16; a1.u = wv.z & 0xffff0000u;
  s += lp[4] * a0.f + lp[5] * a1.f;
  a0.u = wv.w << 16; a1.u = wv.w & 0xffff0000u;
  s += lp[6] * a0.f + lp[7] * a1.f;
  return s;
}

// g' -> g permutation (shared by Wk/Wr repack and bias/wl)
__device__ __forceinline__ int gperm(int gp) {
  if (gp < 16) return gp;
  int r = gp - 16;
  int q = r & 3, h = r >> 2;
  return 16 + q * 384 + h;
}

// ------------------------- dtype detection (safety) ------------------------
__global__ void k_detect(const unsigned int* __restrict__ emb_raw,
                         int* __restrict__ flag) {
  if (blockIdx.x == 0 && threadIdx.x == 0) {
    int cnt = 0;
    for (int i = 64; i < 128; ++i) {
      unsigned int u = emb_raw[i];
      unsigned int lo = u & 0xffffu;
      unsigned int ex = (lo >> 7) & 0xffu;
      if (lo != 0 && ex >= 100 && ex <= 126) ++cnt;
    }
    *flag = (cnt >= 32) ? 1 : 0;
  }
}

// ------------------------- canonicalization --------------------------------
__global__ void k_cvt_emb(const void* __restrict__ src, u16* __restrict__ dst,
                          const int* __restrict__ flagp) {
  int isbf = *flagp;
  int n = 10001 * 128;
  int i = blockIdx.x * blockDim.x + threadIdx.x;
  int stride = gridDim.x * blockDim.x;
  for (; i < n; i += stride)
    dst[i] = isbf ? ((const u16*)src)[i] : f2bf(((const float*)src)[i]);
}

// wkp rows stored in g'-order, padded to 1792 rows (7 tiles of 256)
__global__ void k_repack_wk(const void* __restrict__ wk, u16* __restrict__ wkp,
                            const int* __restrict__ flagp) {
  int isbf = *flagp;
  size_t i = (size_t)blockIdx.x * blockDim.x + threadIdx.x;
  size_t total = (size_t)1792 * 8192;
  size_t stride = (size_t)gridDim.x * blockDim.x;
  for (; i < total; i += stride) {
    size_t gp = i >> 13, k = i & 8191;
    u16 v = (u16)0;
    if (gp < 1552) {
      int g = gperm((int)gp);
      v = f2bf(ldf(wk, (size_t)g * 8193 + k, isbf));
    }
    wkp[i] = v;
  }
}

// wrP2[g'][k] bf16 (permuted g'); biasC/wlC also in g'-order
__global__ void k_prep_wr2(const void* __restrict__ wr, const void* __restrict__ wk,
                           const void* __restrict__ bk, const void* __restrict__ br,
                           u16* __restrict__ wrP2, float* __restrict__ biasC,
                           float* __restrict__ wlC, const int* __restrict__ flagp) {
  int isbf = *flagp;
  int i0 = blockIdx.x * blockDim.x + threadIdx.x;
  int stride = gridDim.x * blockDim.x;
  for (int j = i0; j < 1552 * 384; j += stride) {
    int gp = j / 384, k = j - gp * 384;
    int g = gperm(gp);
    wrP2[j] = f2bf(ldf(wr, (size_t)g * 385 + k, isbf));
  }
  for (int gp = i0; gp < 1552; gp += stride) {
    int g = gperm(gp);
    biasC[gp] = ldf(bk, g, isbf) + ldf(br, g, isbf);
    wlC[gp] = ldf(wk, (size_t)g * 8193 + 8192, isbf) + ldf(wr, g * 385 + 384, isbf);
  }
}

__global__ void k_repack_wc(const void* __restrict__ wc, u16* __restrict__ wcp,
                            const int* __restrict__ flagp) {
  int isbf = *flagp;
  int i0 = blockIdx.x * blockDim.x + threadIdx.x;
  int stride = gridDim.x * blockDim.x;
  for (int j = i0; j < 384 * 3840; j += stride) {
    int o = j / 3840;
    int r = j - o * 3840;
    int k = r / 384;
    int h = r - k * 384;
    wcp[j] = f2bf(ldf(wc, (o * 384 + h) * 10 + k, isbf));  // [o][h][k]->[o][k][h]
  }
}

// canonical fp32: [vt 12800][Ws 24576][bs 64][Wrs 24576][brs 384][bc 384]
//                 [Wo 49152][bo 128]  (total 112064 floats)
__global__ void k_cvt_smalls(const void* vt, const void* Ws, const void* bs,
                             const void* Wrs, const void* brs, const void* bc,
                             const void* Wo, const void* bo,
                             float* __restrict__ dst, const int* __restrict__ flagp) {
  int isbf = *flagp;
  int i = blockIdx.x * blockDim.x + threadIdx.x;
  int stride = gridDim.x * blockDim.x;
  for (; i < 112064; i += stride) {
    float v;
    if (i < 12800) v = ldf(vt, i, isbf);
    else if (i < 37376) v = ldf(Ws, i - 12800, isbf);
    else if (i < 37440) v = ldf(bs, i - 37376, isbf);
    else if (i < 62016) v = ldf(Wrs, i - 37440, isbf);
    else if (i < 62400) v = ldf(brs, i - 62016, isbf);
    else if (i < 62784) v = ldf(bc, i - 62400, isbf);
    else if (i < 111936) v = ldf(Wo, i - 62784, isbf);
    else v = ldf(bo, i - 111936, isbf);
    dst[i] = v;
  }
}

__global__ void k_zero(float* __restrict__ p, int n) {
  int i = blockIdx.x * blockDim.x + threadIdx.x;
  int stride = gridDim.x * blockDim.x;
  for (; i < n; i += stride) p[i] = 0.f;
}

// ------------------------- PH1: gathered GEMM, 256x256 tiles ---------------
// 350 jobs = 7 g-panels x 50 t-tiles (m-tile = one full t: rows = 256 b).
// Panel-clustered bijective XCD map: xcd=lin&7; xcd<6 -> 44 jobs else 43.
// 512 thr = 8 waves (wy=w>>2, wx=w&3); wave output 128x64 (acc[8][4]).
// Staging: 32 chunks (8 rows x 64 cols) per tile, swizzled GLL (chunk
// c^(r&7)), ids register-cached per kt-pair. Same verified read swizzle.
__global__ __launch_bounds__(512, 2) void k_gemm_xk(
    const int* __restrict__ node_ids, const u16* __restrict__ embB,
    const u16* __restrict__ wkp, const float* __restrict__ vtF,
    const float* __restrict__ biasC, const float* __restrict__ wlC,
    u16* __restrict__ xkb) {
  __shared__ alignas(16) u16 As[256 * 64];
  __shared__ alignas(16) u16 Bs[256 * 64];
  int tid = threadIdx.x;
  int lin = blockIdx.x;
  int xcd = lin & 7, slot = lin >> 3;
  int job = (xcd < 6) ? (xcd * 44 + slot) : (264 + (xcd - 6) * 43 + slot);
  int gb = job / 50, mb = job % 50;
  int m0 = mb * 256;  // rows m0..m0+255 = (t=mb, b=0..255)
  int g0 = gb * 256;
  int tq = mb;
  int lane = tid & 63, w = tid >> 6;
  int wy = w >> 2, wx = w & 3;
  f32x4 acc[8][4];
#pragma unroll
  for (int i = 0; i < 8; ++i)
#pragma unroll
    for (int j = 0; j < 4; ++j) acc[i][j] = (f32x4){0.f, 0.f, 0.f, 0.f};

  int l15 = lane & 15, lq = lane >> 4;
  int lr = lane >> 3, lc = lane & 7;  // row-in-chunk, 16B-chunk slot
  int swc = (lc ^ lr) * 8;            // swizzled global chunk offset (u16)
  int cRd = (lq ^ (l15 & 7)) * 8;     // swizzled read chunk, ks=0 (u16)

  int rowA[4];
#pragma unroll
  for (int c = 0; c < 4; ++c) rowA[c] = (w * 4 + c) * 8 + lr;
  int id4[4];

  for (int kt = 0; kt < 128; ++kt) {
    if (!(kt & 1)) {
#pragma unroll
      for (int c = 0; c < 4; ++c)
        id4[c] = node_ids[((size_t)rowA[c] * 50 + tq) * 64 + (kt >> 1)];
    }
    __syncthreads();
    // ---- stage A (gathered embed rows), swizzled global chunk
#pragma unroll
    for (int c = 0; c < 4; ++c) {
      int chunk = w * 4 + c;
      const u16* gp = embB + (size_t)id4[c] * 128 + (kt & 1) * 64 + swc;
      GLL(gp, As + chunk * 512 + lane * 8);
    }
    // ---- stage B (Wk tile, g'-ordered rows), swizzled global chunk
#pragma unroll
    for (int c = 0; c < 4; ++c) {
      int chunk = w * 4 + c;
      int r = chunk * 8 + lr;
      const u16* gp = wkp + (size_t)(g0 + r) * 8192 + (size_t)kt * 64 + swc;
      GLL(gp, Bs + chunk * 512 + lane * 8);
    }
    __syncthreads();
    const u16* Ab = As + (wy * 128 + l15) * 64;
    const u16* Bb = Bs + (wx * 64 + l15) * 64;
#pragma unroll
    for (int ks = 0; ks < 2; ++ks) {
      int co = cRd ^ (ks * 32);
      bf16x8 av[8], bv[4];
#pragma unroll
      for (int i = 0; i < 8; ++i) av[i] = *(const bf16x8*)(Ab + i * 1024 + co);
#pragma unroll
      for (int j = 0; j < 4; ++j) bv[j] = *(const bf16x8*)(Bb + j * 1024 + co);
#pragma unroll
      for (int i = 0; i < 8; ++i)
#pragma unroll
        for (int j = 0; j < 4; ++j)
          acc[i][j] =
              __builtin_amdgcn_mfma_f32_16x16x32_bf16(av[i], bv[j], acc[i][j], 0, 0, 0);
    }
  }
  float vt[8][4];
#pragma unroll
  for (int i = 0; i < 8; ++i)
#pragma unroll
    for (int p = 0; p < 4; ++p)
      vt[i][p] = vtF[(size_t)(wy * 128 + i * 16 + lq * 4 + p) * 50 + tq];
#pragma unroll
  for (int j = 0; j < 4; ++j) {
    int gcol = g0 + wx * 64 + j * 16 + l15;  // g' index, lane-contiguous
    if (gcol < 1552) {
      float bC = biasC[gcol], wC = wlC[gcol];
#pragma unroll
      for (int i = 0; i < 8; ++i)
#pragma unroll
        for (int p = 0; p < 4; ++p) {
          int row = wy * 128 + i * 16 + lq * 4 + p;
          xkb[(size_t)(m0 + row) * 1552 + gcol] =
              f2bf(acc[i][j][p] + bC + vt[i][p] * wC);
        }
    }
  }
}

// ------------------------- PH2: persistent LLC-coherent scan ---------------
// 192 blocks (1/CU via 128KB LDS), 512 thr = 8 waves. Wr slice LDS-resident.
// Per step: h via RELAXED agent atomics (LLC point, no cache flushes);
// MFMA + in-register gates; 12-block monotonic counter barrier (relaxed).
__global__ __launch_bounds__(512) void k_scan5(
    const u16* __restrict__ xkb,        // [50][256][1552] bf16, permuted g'
    const u16* __restrict__ wrP2,       // [1552][384] bf16, permuted g'
    float* __restrict__ hbuf,           // [50][256][384] f32
    float* __restrict__ dbuf,           // [50][256] f32
    unsigned int* __restrict__ hx,      // [2][256][192] u32 packed bf16, zeroed
    int* __restrict__ barCnt) {         // [16] zeroed
  __shared__ alignas(16) u16 WrS[144 * 392];   // 112896B
  __shared__ alignas(16) u16 hS[16 * 392];     // 12544B
  __shared__ alignas(16) float fmTile[16 * 17];
  __shared__ float fmS[16][8], imS[16][8];

  int tid = threadIdx.x;
  int L = blockIdx.x;
  int xcd = L & 7, kk = L >> 3;
  int hi = (kk >= 12) ? 1 : 0;
  int bg = (xcd << 1) | hi;   // b-group [0,16)
  int gs = kk - 12 * hi;      // g-slice [0,12)
  int b0 = bg * 16;
  int wv = tid >> 6, lane = tid & 63, l15 = lane & 15, lq = lane >> 4;

  // one-time: Wr slab -> LDS (rows 0..15 fm/im, 16..143 gate rows of slice)
  for (int idx = tid; idx < 144 * 48; idx += 512) {
    int r = idx / 48, c = idx - r * 48;
    int gr = (r < 16) ? r : (16 + gs * 128 + (r - 16));
    *(uint4*)(WrS + r * 392 + c * 8) =
        *(const uint4*)(wrP2 + (size_t)gr * 384 + c * 8);
  }

  int hmy = gs * 32 + wv * 4 + lq;
  int lmy = hmy / 48;
  int bmy = b0 + l15;
  float creg = 0.f;

  const u16* arow_g = WrS + (16 + wv * 16 + l15) * 392 + lq * 8;
  const u16* arow_f = WrS + l15 * 392 + lq * 8;
  const u16* brow = hS + l15 * 392 + lq * 8;
  __syncthreads();

  for (int t = 0; t < 50; ++t) {
    // ---- xk prefetch (plain loads; xkb is read-only, stream-ordered)
    uint2 xkg = *(const uint2*)(xkb + ((size_t)t * 256 + bmy) * 1552 + 16 +
                                gs * 128 + wv * 16 + lq * 4);
    uint4 xksm = (uint4){0u, 0u, 0u, 0u};
    if (tid < 32)
      xksm = *(const uint4*)(xkb + ((size_t)t * 256 + b0 + (tid & 15)) * 1552 +
                             ((tid < 16) ? 0 : 8));

    // ---- stage h_{t-1} from hx[t&1] via relaxed agent atomic loads (LLC)
    {
      const unsigned int* hxin = hx + (size_t)(t & 1) * 49152 + (size_t)b0 * 192;
#pragma unroll
      for (int k2 = 0; k2 < 6; ++k2) {
        int j = tid + k2 * 512;
        int r = j / 192, c = j - r * 192;
        unsigned int v = __hip_atomic_load(&hxin[r * 192 + c], __ATOMIC_RELAXED,
                                           __HIP_MEMORY_SCOPE_AGENT);
        *(unsigned int*)((char*)hS + r * 784 + c * 4) = v;
      }
    }
    __syncthreads();

    // ---- B-frags (h_{t-1})
    bf16x8 hb[12];
#pragma unroll
    for (int ks = 0; ks < 12; ++ks)
      hb[ks] = *(const bf16x8*)(brow + ks * 32);

    // ---- MFMA: gate tile (all waves) + fm/im tile (wave 0)
    f32x4 accg = (f32x4){0.f, 0.f, 0.f, 0.f};
    f32x4 accf = (f32x4){0.f, 0.f, 0.f, 0.f};
#pragma unroll
    for (int ks = 0; ks < 12; ++ks) {
      bf16x8 ag = *(const bf16x8*)(arow_g + ks * 32);
      accg = __builtin_amdgcn_mfma_f32_16x16x32_bf16(ag, hb[ks], accg, 0, 0, 0);
      if (wv == 0) {
        bf16x8 a0 = *(const bf16x8*)(arow_f + ks * 32);
        accf = __builtin_amdgcn_mfma_f32_16x16x32_bf16(a0, hb[ks], accf, 0, 0, 0);
      }
    }
    if (wv == 0) {
#pragma unroll
      for (int p = 0; p < 4; ++p) fmTile[(lq * 4 + p) * 17 + l15] = accf[p];
    }
    __syncthreads();

    // ---- fm/im softmax (fm: tid<16, im: tid 16..31)
    if (tid < 32) {
      int r = tid & 15;
      const u16* xs = (const u16*)&xksm;
      float z[8], m = -1e30f;
#pragma unroll
      for (int j = 0; j < 8; ++j) {
        int jj = (tid < 16) ? j : (8 + j);
        z[j] = fmTile[jj * 17 + r] + bf2f(xs[j]);
        m = fmaxf(m, z[j]);
      }
      float s = 0.f;
#pragma unroll
      for (int j = 0; j < 8; ++j) { z[j] = __expf(z[j] - m); s += z[j]; }
      float inv = 1.f / s;
      if (tid < 16) {
        float run = 0.f, fsum = 0.f;
#pragma unroll
        for (int j = 0; j < 8; ++j) { run += z[j] * inv; fmS[r][j] = run; fsum += run; }
        if (gs == 0) dbuf[(size_t)t * 256 + b0 + r] = 1.f - fsum * 0.125f;
      } else {
        float run = 0.f;
#pragma unroll
        for (int j = 7; j >= 0; --j) { run += z[j] * inv; imS[r][j] = run; }
      }
    }
    __syncthreads();

    // ---- gates, fully in-register (one (b,h) cell per lane)
    {
      const u16* xg = (const u16*)&xkg;
      float x0 = accg[0] + bf2f(xg[0]);
      float x1 = accg[1] + bf2f(xg[1]);
      float x2 = accg[2] + bf2f(xg[2]);
      float x3 = accg[3] + bf2f(xg[3]);
      float fg = sigf(x0), ig = sigf(x1), og = sigf(x2), ci = tanhf_(x3);
      float fm = fmS[l15][lmy], im = imS[l15][lmy];
      float ov = fm * im;
      float cn = ov * (fg * creg + ig * ci) + (fm - ov) * creg + (im - ov) * ci;
      float hn = og * tanhf_(cn);
      creg = cn;
      hbuf[((size_t)t * 256 + bmy) * 384 + hmy] = hn;
      if (t != 49) {
        unsigned int v = (unsigned int)f2bf(hn);
        unsigned int up = __shfl_down(v, 16);
        if ((lq & 1) == 0) {
          unsigned int packed = v | (up << 16);
          __hip_atomic_store(
              &hx[(size_t)((t + 1) & 1) * 49152 + (size_t)bmy * 192 + gs * 16 +
                  wv * 2 + (lq >> 1)],
              packed, __ATOMIC_RELAXED, __HIP_MEMORY_SCOPE_AGENT);
        }
      }
    }

    // ---- 12-block group barrier (relaxed-only; skip after last step)
    if (t != 49) {
      asm volatile("s_waitcnt vmcnt(0)" ::: "memory");
      __syncthreads();
      if (tid == 0) {
        __hip_atomic_fetch_add(&barCnt[bg], 1, __ATOMIC_RELAXED,
                               __HIP_MEMORY_SCOPE_AGENT);
        while (__hip_atomic_load(&barCnt[bg], __ATOMIC_RELAXED,
                                 __HIP_MEMORY_SCOPE_AGENT) < 12 * (t + 1)) {
          __builtin_amdgcn_s_sleep(1);
        }
      }
      __syncthreads();
    }
  }
}

// ------------------------- PH3: final (theme/conv/out) ---------------------
__global__ __launch_bounds__(384) void k_final(
    const float* __restrict__ hbuf, const float* __restrict__ dbuf,
    const unsigned char* __restrict__ am, const float* __restrict__ smalls,
    const u16* __restrict__ wcp, float* __restrict__ out) {
  const float* WsF = smalls + 12800;
  const float* bsF = smalls + 37376;
  const float* WrsF = smalls + 37440;
  const float* brsF = smalls + 62016;
  const float* bcF = smalls + 62400;
  const float* WoF = smalls + 62784;
  const float* boF = smalls + 111936;
  __shared__ alignas(16) float lh2[10][384];
  __shared__ alignas(16) float ti[384];
  __shared__ alignas(16) float us[64];
  __shared__ alignas(16) float rnnS[384];
  __shared__ alignas(16) float hlastS[384];
  __shared__ float ldS[10];
  __shared__ int npad[50];
  __shared__ int lastS;
  int tid = threadIdx.x;
  int b = blockIdx.x;

  if (tid < 50) {
    const unsigned char* mr = am + ((size_t)b * 50 + tid) * 64;
    int all1 = 1;
    for (int q = 0; q < 64; ++q) all1 &= (mr[q] != 0);
    npad[tid] = all1 ? 0 : 1;
  }
  __syncthreads();
  if (tid == 0) {
    int c = 0;
    for (int v = 0; v < 50; ++v) c += npad[v];
    int lv = c - 1;
    int last = lv < 0 ? 0 : lv;
    lastS = last;
    float cum = 0.f, cv[10];
    for (int k = 0; k < 10; ++k) {
      int s = last - 9 + k;
      float dk = (s >= 0) ? dbuf[(size_t)s * 256 + b] : 0.f;
      cum += dk;
      cv[k] = cum;
    }
    float m = cv[0];
    for (int k = 1; k < 10; ++k) m = fmaxf(m, cv[k]);
    float ssum = 0.f, ee[10];
    for (int k = 0; k < 10; ++k) { ee[k] = __expf(cv[k] - m); ssum += ee[k]; }
    float inv = 1.f / ssum;
    for (int k = 0; k < 10; ++k) ldS[k] = ee[k] * inv;
  }
  __syncthreads();
  {  // local_h, theme input, h_last
    int h = tid;
    int last = lastS;
    float ssum = 0.f;
    for (int k = 0; k < 10; ++k) {
      int s = last - 9 + k;
      float hv = (s >= 0) ? hbuf[((size_t)s * 256 + b) * 384 + h] : 0.f;
      float v = hv * ldS[k];
      lh2[k][h] = v;
      ssum += v;
    }
    ti[h] = ssum * 0.1f;
    hlastS[h] = hbuf[((size_t)last * 256 + b) * 384 + h];
  }
  __syncthreads();
  if (tid < 64) {  // u = relu(ti @ Ws^T + bs)
    float a = bsF[tid];
    const float* wr = WsF + (size_t)tid * 384;
    for (int h = 0; h < 384; ++h) a += wr[h] * ti[h];
    us[tid] = fmaxf(a, 0.f);
  }
  __syncthreads();
  {  // theme = sigmoid(u @ Wrs^T + brs); conv; rnn = theme*conv + h_last
    int o = tid;
    float th = brsF[o];
    const float* wr = WrsF + (size_t)o * 64;
    for (int k = 0; k < 64; ++k) th += wr[k] * us[k];
    th = sigf(th);
    float cacc = bcF[o];
    for (int k = 0; k < 10; ++k) {
      const u16* wrow = wcp + ((size_t)o * 10 + k) * 384;
      const float* lrow = lh2[k];
      for (int h8 = 0; h8 < 48; ++h8) cacc += dot8_bf(wrow + h8 * 8, lrow + h8 * 8);
    }
    rnnS[o] = th * cacc + hlastS[o];
  }
  __syncthreads();
  if (tid < 128) {  // out = rnn @ Wo^T + bo, fp32
    float a = boF[tid];
    const float* wr = WoF + (size_t)tid * 384;
    for (int h = 0; h < 384; ++h) a += wr[h] * rnnS[h];
    out[(size_t)b * 128 + tid] = a;
  }
}

// ------------------------- launch ------------------------------------------
extern "C" void kernel_launch(void* const* d_in, const int* in_sizes, int n_in,
                              void* d_out, int out_size, void* d_ws, size_t ws_size,
                              hipStream_t stream) {
  const int* node_ids = (const int*)d_in[0];
  const void* vtR = d_in[3];
  const unsigned char* am = (const unsigned char*)d_in[5];
  const void* embR = d_in[6];
  const void* WkR = d_in[7];
  const void* bkR = d_in[8];
  const void* WrR = d_in[9];
  const void* brR = d_in[10];
  const void* WsR = d_in[11];
  const void* bsR = d_in[12];
  const void* WrsR = d_in[13];
  const void* brsR = d_in[14];
  const void* WcR = d_in[15];
  const void* bcR = d_in[16];
  const void* WoR = d_in[17];
  const void* boR = d_in[18];
  (void)in_sizes; (void)n_in; (void)out_size; (void)ws_size;

  char* ws = (char*)d_ws;
  size_t off = 0;
  auto alloc = [&](size_t bytes) {
    void* p = ws + off;
    off = (off + bytes + 255) & ~(size_t)255;
    return p;
  };
  int* flagp = (int*)alloc(4);
  u16* embB = (u16*)alloc((size_t)10001 * 128 * 2);      // 2.56MB
  u16* WkP = (u16*)alloc((size_t)1792 * 8192 * 2);       // 29.4MB g'-ordered
  u16* WrP2 = (u16*)alloc((size_t)1552 * 384 * 2);       // 1.19MB bf16 permuted
  float* biasC = (float*)alloc(1552 * 4);
  float* wlC = (float*)alloc(1552 * 4);
  float* smalls = (float*)alloc((size_t)112064 * 4);
  u16* XKb = (u16*)alloc((size_t)12800 * 1552 * 2);      // 39.7MB [t][b][g']
  u16* WcP = (u16*)alloc((size_t)384 * 3840 * 2);        // 2.9MB
  float* Hbuf = (float*)alloc((size_t)50 * 256 * 384 * 4);  // 19.7MB
  float* Dbuf = (float*)alloc((size_t)50 * 256 * 4);
  unsigned int* Hx = (unsigned int*)alloc((size_t)2 * 256 * 192 * 4);  // 393KB
  int* BarCnt = (int*)alloc(16 * 4);

  k_detect<<<dim3(1), dim3(64), 0, stream>>>((const unsigned int*)embR, flagp);
  k_cvt_emb<<<dim3(1024), dim3(256), 0, stream>>>(embR, embB, flagp);
  k_repack_wk<<<dim3(2048), dim3(256), 0, stream>>>(WkR, WkP, flagp);
  k_prep_wr2<<<dim3(512), dim3(256), 0, stream>>>(WrR, WkR, bkR, brR, WrP2, biasC,
                                                  wlC, flagp);
  k_repack_wc<<<dim3(512), dim3(256), 0, stream>>>(WcR, WcP, flagp);
  k_cvt_smalls<<<dim3(128), dim3(256), 0, stream>>>(vtR, WsR, bsR, WrsR, brsR,
                                                    bcR, WoR, boR, smalls, flagp);
  k_zero<<<dim3(96), dim3(256), 0, stream>>>((float*)Hx, 98304);
  k_zero<<<dim3(1), dim3(64), 0, stream>>>((float*)BarCnt, 16);

  k_gemm_xk<<<dim3(350), dim3(512), 0, stream>>>(node_ids, embB, WkP, smalls,
                                                 biasC, wlC, XKb);

  k_scan5<<<dim3(192), dim3(512), 0, stream>>>(XKb, WrP2, Hbuf, Dbuf, Hx, BarCnt);

  k_final<<<dim3(256), dim3(384), 0, stream>>>(Hbuf, Dbuf, am, smalls, WcP,
                                               (float*)d_out);
}

// Round 11
// 961.279 us; speedup vs baseline: 1.1477x; 1.1477x over previous
//
#include <hip/hip_runtime.h>
#include <stdint.h>

// ---------------------------------------------------------------------------
// StageNet forward on MI355X — ROUND 22.
// R21 (1103us): 256^2 gemm regressed (350 blocks -> imbalance + no TLP to
// hide GLL ingest; VALUBusy 40->10%). REVERT gemm to R20's 128^2 (490us).
// Scan (430us, 8.6us/step) restructured toward its ~4-5us/step floor:
//  * in-register fm/im softmax: every wave computes tile0 MFMA (+12, cheap);
//    softmax via shfl_xor(16) pair reduce + prefix; lmy=(gs*32+wv*4)/48 is
//    wave-uniform (4-aligned runs never cross 48) -> uniform reg-select +
//    one shfl delivers fm/im to gate lanes. Kills 2 syncthreads + fm LDS.
//  * deferred hbuf/dbuf archive writes (issued next step) -> pre-barrier
//    vmcnt(0) drains only the 4B hx exchange stores, not HBM writes.
//  * dead gate-phase hS write removed.
// Predicted: scan 240-300us, gemm ~490, total ~830-900us.
// ---------------------------------------------------------------------------

typedef unsigned short u16;
typedef short bf16x8 __attribute__((ext_vector_type(8)));
typedef float f32x4 __attribute__((ext_vector_type(4)));

#define GLL(gp, lp)                                                            \
  __builtin_amdgcn_global_load_lds(                                            \
      (const __attribute__((address_space(1))) unsigned int*)(gp),             \
      (__attribute__((address_space(3))) unsigned int*)(lp), 16, 0, 0)

__device__ __forceinline__ float bf2f(u16 u) {
  union { unsigned int i; float f; } v;
  v.i = ((unsigned int)u) << 16;
  return v.f;
}
__device__ __forceinline__ u16 f2bf(float f) {
  union { float f; unsigned int i; } v;
  v.f = f;
  unsigned int r = (v.i + 0x7fffu + ((v.i >> 16) & 1u)) >> 16;
  return (u16)r;
}
__device__ __forceinline__ float ldf(const void* p, size_t i, int isbf) {
  return isbf ? bf2f(((const u16*)p)[i]) : ((const float*)p)[i];
}
__device__ __forceinline__ float sigf(float x) { return 1.f / (1.f + __expf(-x)); }
__device__ __forceinline__ float tanhf_(float x) {
  float cx = fminf(fmaxf(x, -15.f), 15.f);
  float e = __expf(2.f * cx);
  return (e - 1.f) / (e + 1.f);
}
__device__ __forceinline__ float dot8_bf(const u16* w, const float* lp) {
  uint4 wv = *(const uint4*)w;
  union { unsigned int u; float f; } a0, a1;
  float s;
  a0.u = wv.x << 16; a1.u = wv.x & 0xffff0000u;
  s = lp[0] * a0.f + lp[1] * a1.f;
  a0.u = wv.y << 16; a1.u = wv.y & 0xffff0000u;
  s += lp[2] * a0.f + lp[3] * a1.f;
  a0.u = wv.z << 16; a1.u = wv.z & 0xffff0000u;
  s += lp[4] * a0.f + lp[5] * a1.f;
  a0.u = wv.w << 16; a1.u = wv.w & 0xffff0000u;
  s += lp[6] * a0.f + lp[7] * a1.f;
  return s;
}

// g' -> g permutation (shared by Wk/Wr repack and bias/wl)
__device__ __forceinline__ int gperm(int gp) {
  if (gp < 16) return gp;
  int r = gp - 16;
  int q = r & 3, h = r >> 2;
  return 16 + q * 384 + h;
}

// ------------------------- dtype detection (safety) ------------------------
__global__ void k_detect(const unsigned int* __restrict__ emb_raw,
                         int* __restrict__ flag) {
  if (blockIdx.x == 0 && threadIdx.x == 0) {
    int cnt = 0;
    for (int i = 64; i < 128; ++i) {
      unsigned int u = emb_raw[i];
      unsigned int lo = u & 0xffffu;
      unsigned int ex = (lo >> 7) & 0xffu;
      if (lo != 0 && ex >= 100 && ex <= 126) ++cnt;
    }
    *flag = (cnt >= 32) ? 1 : 0;
  }
}

// ------------------------- canonicalization --------------------------------
__global__ void k_cvt_emb(const void* __restrict__ src, u16* __restrict__ dst,
                          const int* __restrict__ flagp) {
  int isbf = *flagp;
  int n = 10001 * 128;
  int i = blockIdx.x * blockDim.x + threadIdx.x;
  int stride = gridDim.x * blockDim.x;
  for (; i < n; i += stride)
    dst[i] = isbf ? ((const u16*)src)[i] : f2bf(((const float*)src)[i]);
}

// wkp rows stored in g'-order (tile-local gate quads -> contiguous epilogue)
__global__ void k_repack_wk(const void* __restrict__ wk, u16* __restrict__ wkp,
                            const int* __restrict__ flagp) {
  int isbf = *flagp;
  size_t i = (size_t)blockIdx.x * blockDim.x + threadIdx.x;
  size_t total = (size_t)1664 * 8192;
  size_t stride = (size_t)gridDim.x * blockDim.x;
  for (; i < total; i += stride) {
    size_t gp = i >> 13, k = i & 8191;
    u16 v = (u16)0;
    if (gp < 1552) {
      int g = gperm((int)gp);
      v = f2bf(ldf(wk, (size_t)g * 8193 + k, isbf));
    }
    wkp[i] = v;
  }
}

// wrP2[g'][k] bf16 (permuted g'); biasC/wlC also in g'-order
__global__ void k_prep_wr2(const void* __restrict__ wr, const void* __restrict__ wk,
                           const void* __restrict__ bk, const void* __restrict__ br,
                           u16* __restrict__ wrP2, float* __restrict__ biasC,
                           float* __restrict__ wlC, const int* __restrict__ flagp) {
  int isbf = *flagp;
  int i0 = blockIdx.x * blockDim.x + threadIdx.x;
  int stride = gridDim.x * blockDim.x;
  for (int j = i0; j < 1552 * 384; j += stride) {
    int gp = j / 384, k = j - gp * 384;
    int g = gperm(gp);
    wrP2[j] = f2bf(ldf(wr, (size_t)g * 385 + k, isbf));
  }
  for (int gp = i0; gp < 1552; gp += stride) {
    int g = gperm(gp);
    biasC[gp] = ldf(bk, g, isbf) + ldf(br, g, isbf);
    wlC[gp] = ldf(wk, (size_t)g * 8193 + 8192, isbf) + ldf(wr, g * 385 + 384, isbf);
  }
}

__global__ void k_repack_wc(const void* __restrict__ wc, u16* __restrict__ wcp,
                            const int* __restrict__ flagp) {
  int isbf = *flagp;
  int i0 = blockIdx.x * blockDim.x + threadIdx.x;
  int stride = gridDim.x * blockDim.x;
  for (int j = i0; j < 384 * 3840; j += stride) {
    int o = j / 3840;
    int r = j - o * 3840;
    int k = r / 384;
    int h = r - k * 384;
    wcp[j] = f2bf(ldf(wc, (o * 384 + h) * 10 + k, isbf));  // [o][h][k]->[o][k][h]
  }
}

// canonical fp32: [vt 12800][Ws 24576][bs 64][Wrs 24576][brs 384][bc 384]
//                 [Wo 49152][bo 128]  (total 112064 floats)
__global__ void k_cvt_smalls(const void* vt, const void* Ws, const void* bs,
                             const void* Wrs, const void* brs, const void* bc,
                             const void* Wo, const void* bo,
                             float* __restrict__ dst, const int* __restrict__ flagp) {
  int isbf = *flagp;
  int i = blockIdx.x * blockDim.x + threadIdx.x;
  int stride = gridDim.x * blockDim.x;
  for (; i < 112064; i += stride) {
    float v;
    if (i < 12800) v = ldf(vt, i, isbf);
    else if (i < 37376) v = ldf(Ws, i - 12800, isbf);
    else if (i < 37440) v = ldf(bs, i - 37376, isbf);
    else if (i < 62016) v = ldf(Wrs, i - 37440, isbf);
    else if (i < 62400) v = ldf(brs, i - 62016, isbf);
    else if (i < 62784) v = ldf(bc, i - 62400, isbf);
    else if (i < 111936) v = ldf(Wo, i - 62784, isbf);
    else v = ldf(bo, i - 111936, isbf);
    dst[i] = v;
  }
}

__global__ void k_zero(float* __restrict__ p, int n) {
  int i = blockIdx.x * blockDim.x + threadIdx.x;
  int stride = gridDim.x * blockDim.x;
  for (; i < n; i += stride) p[i] = 0.f;
}

// ------------------------- PH1: gathered GEMM (R20 proven) -----------------
// Linear grid 1300, panel-clustered XCD mapping (xcd=lin&7). Tile 128x128,
// BK=64 bf16. node_ids staged once to LDS (u16, stride 66 = bank-spread).
// Wk/bias/wl in g'-order; epilogue stores g'-contiguous.
__global__ __launch_bounds__(256) void k_gemm_xk(
    const int* __restrict__ node_ids, const u16* __restrict__ embB,
    const u16* __restrict__ wkp, const float* __restrict__ vtF,
    const float* __restrict__ biasC, const float* __restrict__ wlC,
    u16* __restrict__ xkb) {
  __shared__ alignas(16) u16 As[128 * 64];
  __shared__ alignas(16) u16 Bs[128 * 64];
  __shared__ alignas(16) u16 idS[128 * 66];  // stride 66: id reads bank-spread
  int tid = threadIdx.x;
  int lin = blockIdx.x;
  int xcd = lin & 7, slot = lin >> 3;
  int job = (xcd < 4) ? (xcd * 163 + slot) : (4 * 163 + (xcd - 4) * 162 + slot);
  int mb = job % 100, gb = job / 100;
  int m0 = mb * 128;
  int g0 = gb * 128;
  int tq = m0 >> 8, b0t = m0 & 255;
  int lane = tid & 63, w = tid >> 6;
  int wy = w >> 1, wx = w & 1;
  f32x4 acc[4][4];
#pragma unroll
  for (int i = 0; i < 4; ++i)
#pragma unroll
    for (int j = 0; j < 4; ++j) acc[i][j] = (f32x4){0.f, 0.f, 0.f, 0.f};

  // ---- stage node ids once (row-major int4 loads, u16 LDS store)
  {
    const int4* nb = (const int4*)(node_ids + ((size_t)b0t * 50 + tq) * 64);
    for (int i = tid; i < 2048; i += 256) {
      int row = i >> 4, c4 = i & 15;
      int4 v = nb[(size_t)row * 800 + c4];  // row stride 50*64/4 = 800 int4
      u16* d = idS + row * 66 + c4 * 4;
      d[0] = (u16)v.x; d[1] = (u16)v.y; d[2] = (u16)v.z; d[3] = (u16)v.w;
    }
  }

  int l15 = lane & 15, lq = lane >> 4;
  int lr = lane >> 3, lc = lane & 7;
  int swc = (lc ^ lr) * 8;
  int cRd = (lq ^ (l15 & 7)) * 8;

  for (int kt = 0; kt < 128; ++kt) {
    __syncthreads();
#pragma unroll
    for (int c = 0; c < 4; ++c) {
      int chunk = w * 4 + c;
      int r = chunk * 8 + lr;
      int id = (int)idS[r * 66 + (kt >> 1)];
      const u16* gp = embB + (size_t)id * 128 + (kt & 1) * 64 + swc;
      u16* lp = As + chunk * 512 + lane * 8;
      GLL(gp, lp);
    }
#pragma unroll
    for (int c = 0; c < 4; ++c) {
      int chunk = w * 4 + c;
      int r = chunk * 8 + lr;
      const u16* gp = wkp + (size_t)(g0 + r) * 8192 + (size_t)kt * 64 + swc;
      u16* lp = Bs + chunk * 512 + lane * 8;
      GLL(gp, lp);
    }
    __syncthreads();
    const u16* Ab = As + (wy * 64 + l15) * 64;
    const u16* Bb = Bs + (wx * 64 + l15) * 64;
#pragma unroll
    for (int ks = 0; ks < 2; ++ks) {
      int co = cRd ^ (ks * 32);
      bf16x8 av[4], bv[4];
#pragma unroll
      for (int i = 0; i < 4; ++i) av[i] = *(const bf16x8*)(Ab + i * 1024 + co);
#pragma unroll
      for (int j = 0; j < 4; ++j) bv[j] = *(const bf16x8*)(Bb + j * 1024 + co);
#pragma unroll
      for (int i = 0; i < 4; ++i)
#pragma unroll
        for (int j = 0; j < 4; ++j)
          acc[i][j] =
              __builtin_amdgcn_mfma_f32_16x16x32_bf16(av[i], bv[j], acc[i][j], 0, 0, 0);
    }
  }
  float vt[4][4];
#pragma unroll
  for (int i = 0; i < 4; ++i)
#pragma unroll
    for (int p = 0; p < 4; ++p)
      vt[i][p] = vtF[(size_t)(b0t + wy * 64 + i * 16 + lq * 4 + p) * 50 + tq];
#pragma unroll
  for (int j = 0; j < 4; ++j) {
    int gcol = g0 + wx * 64 + j * 16 + l15;
    if (gcol < 1552) {
      float bC = biasC[gcol], wC = wlC[gcol];
#pragma unroll
      for (int i = 0; i < 4; ++i)
#pragma unroll
        for (int p = 0; p < 4; ++p) {
          int row = wy * 64 + i * 16 + lq * 4 + p;
          xkb[(size_t)(m0 + row) * 1552 + gcol] =
              f2bf(acc[i][j][p] + bC + vt[i][p] * wC);
        }
    }
  }
}

// ------------------------- PH2: persistent LLC-coherent scan v6 ------------
// 192 blocks (1/CU via ~113KB LDS), 512 thr = 8 waves. Wr slice LDS-resident.
// Per step: h via RELAXED agent atomics; all waves compute gate tile + fm/im
// tile0 MFMA; softmax fully in-register (shfl_xor pair reduce; lmy is
// wave-uniform since 4-aligned h-runs never cross a 48 boundary); gates
// in-register; hbuf/dbuf archive writes DEFERRED one step (off the vmcnt(0)
// drain); 12-block monotonic counter barrier (relaxed-only).
__global__ __launch_bounds__(512) void k_scan6(
    const u16* __restrict__ xkb,        // [50][256][1552] bf16, permuted g'
    const u16* __restrict__ wrP2,       // [1552][384] bf16, permuted g'
    float* __restrict__ hbuf,           // [50][256][384] f32
    float* __restrict__ dbuf,           // [50][256] f32
    unsigned int* __restrict__ hx,      // [2][256][192] u32 packed bf16, zeroed
    int* __restrict__ barCnt) {         // [16] zeroed
  __shared__ alignas(16) u16 WrS[144 * 392];   // 112896B
  __shared__ alignas(16) u16 hS[16 * 392];     // 12544B

  int tid = threadIdx.x;
  int L = blockIdx.x;
  int xcd = L & 7, kk = L >> 3;
  int hi = (kk >= 12) ? 1 : 0;
  int bg = (xcd << 1) | hi;   // b-group [0,16)
  int gs = kk - 12 * hi;      // g-slice [0,12)
  int b0 = bg * 16;
  int wv = tid >> 6, lane = tid & 63, l15 = lane & 15, lq = lane >> 4;

  // one-time: Wr slab -> LDS (rows 0..15 fm/im, 16..143 gate rows of slice)
  for (int idx = tid; idx < 144 * 48; idx += 512) {
    int r = idx / 48, c = idx - r * 48;
    int gr = (r < 16) ? r : (16 + gs * 128 + (r - 16));
    *(uint4*)(WrS + r * 392 + c * 8) =
        *(const uint4*)(wrP2 + (size_t)gr * 384 + c * 8);
  }

  int hmy = gs * 32 + wv * 4 + lq;
  int lmy = (gs * 32 + wv * 4) / 48;  // wave-uniform level index
  int bmy = b0 + l15;
  float creg = 0.f;
  float hbufPend = 0.f, dvalPend = 0.f;

  const u16* arow_g = WrS + (16 + wv * 16 + l15) * 392 + lq * 8;
  const u16* arow_f = WrS + l15 * 392 + lq * 8;
  const u16* brow = hS + l15 * 392 + lq * 8;
  __syncthreads();

  for (int t = 0; t < 50; ++t) {
    // ---- xk prefetch: gate quad + fm/im quad (plain loads, read-only)
    const u16* xkrow = xkb + ((size_t)t * 256 + bmy) * 1552;
    uint2 xkg = *(const uint2*)(xkrow + 16 + gs * 128 + wv * 16 + lq * 4);
    uint2 xkf = *(const uint2*)(xkrow + lq * 4);

    // ---- stage h_{t-1} from hx[t&1] via relaxed agent atomic loads
    {
      const unsigned int* hxin = hx + (size_t)(t & 1) * 49152 + (size_t)b0 * 192;
#pragma unroll
      for (int k2 = 0; k2 < 6; ++k2) {
        int j = tid + k2 * 512;
        int r = j / 192, c = j - r * 192;
        unsigned int v = __hip_atomic_load(&hxin[r * 192 + c], __ATOMIC_RELAXED,
                                           __HIP_MEMORY_SCOPE_AGENT);
        *(unsigned int*)((char*)hS + r * 784 + c * 4) = v;
      }
    }

    // ---- deferred archive writes for step t-1 (drained by THIS step's
    // pre-barrier vmcnt(0), a full compute phase later)
    if (t > 0) {
      hbuf[((size_t)(t - 1) * 256 + bmy) * 384 + hmy] = hbufPend;
      if (gs == 0 && wv == 0 && lq == 0)
        dbuf[(size_t)(t - 1) * 256 + b0 + l15] = dvalPend;
    }
    __syncthreads();

    // ---- B-frags (h_{t-1})
    bf16x8 hb[12];
#pragma unroll
    for (int ks = 0; ks < 12; ++ks)
      hb[ks] = *(const bf16x8*)(brow + ks * 32);

    // ---- MFMA: gate tile + fm/im tile0 (ALL waves)
    f32x4 accg = (f32x4){0.f, 0.f, 0.f, 0.f};
    f32x4 accf = (f32x4){0.f, 0.f, 0.f, 0.f};
#pragma unroll
    for (int ks = 0; ks < 12; ++ks) {
      bf16x8 ag = *(const bf16x8*)(arow_g + ks * 32);
      bf16x8 a0 = *(const bf16x8*)(arow_f + ks * 32);
      accg = __builtin_amdgcn_mfma_f32_16x16x32_bf16(ag, hb[ks], accg, 0, 0, 0);
      accf = __builtin_amdgcn_mfma_f32_16x16x32_bf16(a0, hb[ks], accf, 0, 0, 0);
    }

    // ---- in-register fm/im softmax.
    // accf[p] = z[b=l15][g'=lq*4+p]. fm: lq<2 (g'0..7), im: lq>=2 (g'8..15).
    // Pair partner via shfl_xor(16): (lq0,lq1), (lq2,lq3).
    float dval;
    float fmv, imv;
    {
      const u16* xf = (const u16*)&xkf;
      float z0 = accf[0] + bf2f(xf[0]);
      float z1 = accf[1] + bf2f(xf[1]);
      float z2 = accf[2] + bf2f(xf[2]);
      float z3 = accf[3] + bf2f(xf[3]);
      float m4 = fmaxf(fmaxf(z0, z1), fmaxf(z2, z3));
      float mm = fmaxf(m4, __shfl_xor(m4, 16));
      float e0 = __expf(z0 - mm), e1 = __expf(z1 - mm);
      float e2 = __expf(z2 - mm), e3 = __expf(z3 - mm);
      float s4 = e0 + e1 + e2 + e3;
      float so = __shfl_xor(s4, 16);
      float inv = 1.f / (s4 + so);
      float cum0, cum1, cum2, cum3;
      if (lq < 2) {  // fm prefix (left-to-right over g' 0..7)
        float base = (lq == 1) ? so : 0.f;
        cum0 = (base + e0) * inv;
        cum1 = (base + e0 + e1) * inv;
        cum2 = (base + e0 + e1 + e2) * inv;
        cum3 = (base + s4) * inv;
      } else {  // im suffix (right-to-left over g' 8..15)
        float base = (lq == 2) ? so : 0.f;
        cum3 = (base + e3) * inv;
        cum2 = (base + e3 + e2) * inv;
        cum1 = (base + e3 + e2 + e1) * inv;
        cum0 = (base + s4) * inv;
      }
      // dval = 1 - mean(fm) (valid on fm lanes)
      float fs4 = cum0 + cum1 + cum2 + cum3;
      float fst = fs4 + __shfl_xor(fs4, 16);
      dval = 1.f - fst * 0.125f;
      // deliver fm/im[lmy] to gate lanes (lmy wave-uniform)
      int r2 = lmy & 3;
      float vsel = cum0;
      if (r2 == 1) vsel = cum1;
      else if (r2 == 2) vsel = cum2;
      else if (r2 == 3) vsel = cum3;
      int srcBase = l15 + ((lmy >> 2) << 4);
      fmv = __shfl(vsel, srcBase);
      imv = __shfl(vsel, srcBase + 32);
    }

    // ---- gates, fully in-register (one (b,h) cell per lane)
    {
      const u16* xg = (const u16*)&xkg;
      float x0 = accg[0] + bf2f(xg[0]);
      float x1 = accg[1] + bf2f(xg[1]);
      float x2 = accg[2] + bf2f(xg[2]);
      float x3 = accg[3] + bf2f(xg[3]);
      float fg = sigf(x0), ig = sigf(x1), og = sigf(x2), ci = tanhf_(x3);
      float ov = fmv * imv;
      float cn = ov * (fg * creg + ig * ci) + (fmv - ov) * creg + (imv - ov) * ci;
      float hn = og * tanhf_(cn);
      creg = cn;
      hbufPend = hn;
      dvalPend = dval;
      if (t != 49) {
        unsigned int v = (unsigned int)f2bf(hn);
        unsigned int up = __shfl_down(v, 16);
        if ((lq & 1) == 0) {
          unsigned int packed = v | (up << 16);
          __hip_atomic_store(
              &hx[(size_t)((t + 1) & 1) * 49152 + (size_t)bmy * 192 + gs * 16 +
                  wv * 2 + (lq >> 1)],
              packed, __ATOMIC_RELAXED, __HIP_MEMORY_SCOPE_AGENT);
        }
      }
    }

    // ---- 12-block group barrier (relaxed-only; skip after last step)
    if (t != 49) {
      asm volatile("s_waitcnt vmcnt(0)" ::: "memory");
      __syncthreads();
      if (tid == 0) {
        __hip_atomic_fetch_add(&barCnt[bg], 1, __ATOMIC_RELAXED,
                               __HIP_MEMORY_SCOPE_AGENT);
        while (__hip_atomic_load(&barCnt[bg], __ATOMIC_RELAXED,
                                 __HIP_MEMORY_SCOPE_AGENT) < 12 * (t + 1)) {
          __builtin_amdgcn_s_sleep(1);
        }
      }
      __syncthreads();
    }
  }
  // final archive writes (step 49)
  hbuf[((size_t)49 * 256 + bmy) * 384 + hmy] = hbufPend;
  if (gs == 0 && wv == 0 && lq == 0) dbuf[(size_t)49 * 256 + b0 + l15] = dvalPend;
}

// ------------------------- PH3: final (theme/conv/out) ---------------------
__global__ __launch_bounds__(384) void k_final(
    const float* __restrict__ hbuf, const float* __restrict__ dbuf,
    const unsigned char* __restrict__ am, const float* __restrict__ smalls,
    const u16* __restrict__ wcp, float* __restrict__ out) {
  const float* WsF = smalls + 12800;
  const float* bsF = smalls + 37376;
  const float* WrsF = smalls + 37440;
  const float* brsF = smalls + 62016;
  const float* bcF = smalls + 62400;
  const float* WoF = smalls + 62784;
  const float* boF = smalls + 111936;
  __shared__ alignas(16) float lh2[10][384];
  __shared__ alignas(16) float ti[384];
  __shared__ alignas(16) float us[64];
  __shared__ alignas(16) float rnnS[384];
  __shared__ alignas(16) float hlastS[384];
  __shared__ float ldS[10];
  __shared__ int npad[50];
  __shared__ int lastS;
  int tid = threadIdx.x;
  int b = blockIdx.x;

  if (tid < 50) {
    const unsigned char* mr = am + ((size_t)b * 50 + tid) * 64;
    int all1 = 1;
    for (int q = 0; q < 64; ++q) all1 &= (mr[q] != 0);
    npad[tid] = all1 ? 0 : 1;
  }
  __syncthreads();
  if (tid == 0) {
    int c = 0;
    for (int v = 0; v < 50; ++v) c += npad[v];
    int lv = c - 1;
    int last = lv < 0 ? 0 : lv;
    lastS = last;
    float cum = 0.f, cv[10];
    for (int k = 0; k < 10; ++k) {
      int s = last - 9 + k;
      float dk = (s >= 0) ? dbuf[(size_t)s * 256 + b] : 0.f;
      cum += dk;
      cv[k] = cum;
    }
    float m = cv[0];
    for (int k = 1; k < 10; ++k) m = fmaxf(m, cv[k]);
    float ssum = 0.f, ee[10];
    for (int k = 0; k < 10; ++k) { ee[k] = __expf(cv[k] - m); ssum += ee[k]; }
    float inv = 1.f / ssum;
    for (int k = 0; k < 10; ++k) ldS[k] = ee[k] * inv;
  }
  __syncthreads();
  {  // local_h, theme input, h_last
    int h = tid;
    int last = lastS;
    float ssum = 0.f;
    for (int k = 0; k < 10; ++k) {
      int s = last - 9 + k;
      float hv = (s >= 0) ? hbuf[((size_t)s * 256 + b) * 384 + h] : 0.f;
      float v = hv * ldS[k];
      lh2[k][h] = v;
      ssum += v;
    }
    ti[h] = ssum * 0.1f;
    hlastS[h] = hbuf[((size_t)last * 256 + b) * 384 + h];
  }
  __syncthreads();
  if (tid < 64) {  // u = relu(ti @ Ws^T + bs)
    float a = bsF[tid];
    const float* wr = WsF + (size_t)tid * 384;
    for (int h = 0; h < 384; ++h) a += wr[h] * ti[h];
    us[tid] = fmaxf(a, 0.f);
  }
  __syncthreads();
  {  // theme = sigmoid(u @ Wrs^T + brs); conv; rnn = theme*conv + h_last
    int o = tid;
    float th = brsF[o];
    const float* wr = WrsF + (size_t)o * 64;
    for (int k = 0; k < 64; ++k) th += wr[k] * us[k];
    th = sigf(th);
    float cacc = bcF[o];
    for (int k = 0; k < 10; ++k) {
      const u16* wrow = wcp + ((size_t)o * 10 + k) * 384;
      const float* lrow = lh2[k];
      for (int h8 = 0; h8 < 48; ++h8) cacc += dot8_bf(wrow + h8 * 8, lrow + h8 * 8);
    }
    rnnS[o] = th * cacc + hlastS[o];
  }
  __syncthreads();
  if (tid < 128) {  // out = rnn @ Wo^T + bo, fp32
    float a = boF[tid];
    const float* wr = WoF + (size_t)tid * 384;
    for (int h = 0; h < 384; ++h) a += wr[h] * rnnS[h];
    out[(size_t)b * 128 + tid] = a;
  }
}

// ------------------------- launch ------------------------------------------
extern "C" void kernel_launch(void* const* d_in, const int* in_sizes, int n_in,
                              void* d_out, int out_size, void* d_ws, size_t ws_size,
                              hipStream_t stream) {
  const int* node_ids = (const int*)d_in[0];
  const void* vtR = d_in[3];
  const unsigned char* am = (const unsigned char*)d_in[5];
  const void* embR = d_in[6];
  const void* WkR = d_in[7];
  const void* bkR = d_in[8];
  const void* WrR = d_in[9];
  const void* brR = d_in[10];
  const void* WsR = d_in[11];
  const void* bsR = d_in[12];
  const void* WrsR = d_in[13];
  const void* brsR = d_in[14];
  const void* WcR = d_in[15];
  const void* bcR = d_in[16];
  const void* WoR = d_in[17];
  const void* boR = d_in[18];
  (void)in_sizes; (void)n_in; (void)out_size; (void)ws_size;

  char* ws = (char*)d_ws;
  size_t off = 0;
  auto alloc = [&](size_t bytes) {
    void* p = ws + off;
    off = (off + bytes + 255) & ~(size_t)255;
    return p;
  };
  int* flagp = (int*)alloc(4);
  u16* embB = (u16*)alloc((size_t)10001 * 128 * 2);      // 2.56MB
  u16* WkP = (u16*)alloc((size_t)1664 * 8192 * 2);       // 27.3MB g'-ordered
  u16* WrP2 = (u16*)alloc((size_t)1552 * 384 * 2);       // 1.19MB bf16 permuted
  float* biasC = (float*)alloc(1552 * 4);
  float* wlC = (float*)alloc(1552 * 4);
  float* smalls = (float*)alloc((size_t)112064 * 4);
  u16* XKb = (u16*)alloc((size_t)12800 * 1552 * 2);      // 39.7MB [t][b][g']
  u16* WcP = (u16*)alloc((size_t)384 * 3840 * 2);        // 2.9MB
  float* Hbuf = (float*)alloc((size_t)50 * 256 * 384 * 4);  // 19.7MB
  float* Dbuf = (float*)alloc((size_t)50 * 256 * 4);
  unsigned int* Hx = (unsigned int*)alloc((size_t)2 * 256 * 192 * 4);  // 393KB
  int* BarCnt = (int*)alloc(16 * 4);

  k_detect<<<dim3(1), dim3(64), 0, stream>>>((const unsigned int*)embR, flagp);
  k_cvt_emb<<<dim3(1024), dim3(256), 0, stream>>>(embR, embB, flagp);
  k_repack_wk<<<dim3(2048), dim3(256), 0, stream>>>(WkR, WkP, flagp);
  k_prep_wr2<<<dim3(512), dim3(256), 0, stream>>>(WrR, WkR, bkR, brR, WrP2, biasC,
                                                  wlC, flagp);
  k_repack_wc<<<dim3(512), dim3(256), 0, stream>>>(WcR, WcP, flagp);
  k_cvt_smalls<<<dim3(128), dim3(256), 0, stream>>>(vtR, WsR, bsR, WrsR, brsR,
                                                    bcR, WoR, boR, smalls, flagp);
  k_zero<<<dim3(96), dim3(256), 0, stream>>>((float*)Hx, 98304);
  k_zero<<<dim3(1), dim3(64), 0, stream>>>((float*)BarCnt, 16);

  k_gemm_xk<<<dim3(1300), dim3(256), 0, stream>>>(node_ids, embB, WkP, smalls,
                                                  biasC, wlC, XKb);

  k_scan6<<<dim3(192), dim3(512), 0, stream>>>(XKb, WrP2, Hbuf, Dbuf, Hx, BarCnt);

  k_final<<<dim3(256), dim3(384), 0, stream>>>(Hbuf, Dbuf, am, smalls, WcP,
                                               (float*)d_out);
}